// Round 2
// baseline (276.424 us; speedup 1.0000x reference)
//
#include <hip/hip_runtime.h>
#include <math.h>

#define NN 20000
#define NE 320000
#define NREL 9
#define NBASES 9
#define D_IN 128
#define D_HID 256
#define D_OUT 64
#define LN_EPS 1e-5f

#define N1 (NREL * D_HID + D_HID)   // 2560
#define N2 (NREL * D_OUT + D_OUT)   // 640
#define NBLK ((NN + 255) / 256)     // 79

typedef __attribute__((ext_vector_type(8))) short bf16x8;
typedef __attribute__((ext_vector_type(4))) float f32x4;

__device__ inline ushort f2b(float f) {
    unsigned u = __float_as_uint(f);
    return (ushort)((u + 0x7FFFu + ((u >> 16) & 1u)) >> 16);
}
__device__ inline float b2f(ushort h) { return __uint_as_float(((unsigned)h) << 16); }
__device__ inline unsigned pack2bf(float f0, float f1) {
    return (unsigned)f2b(f0) | ((unsigned)f2b(f1) << 16);
}

// ---------- fused prep: weights (coalesced basis reads) + x cast + dst histogram ----------
__global__ __launch_bounds__(256) void prep_all(
    const float* __restrict__ bases1, const float* __restrict__ comp1, const float* __restrict__ root1,
    const float* __restrict__ bases2, const float* __restrict__ comp2, const float* __restrict__ root2,
    const float* __restrict__ x, const int* __restrict__ dst,
    ushort* __restrict__ w1t, ushort* __restrict__ w2t, ushort* __restrict__ xbf,
    int* __restrict__ deg)
{
    const int SZW1 = D_IN * D_HID;   // 32768
    const int SZW2 = D_HID * D_OUT;  // 16384
    const int SZX  = NN * D_IN;      // 2560000
    int tid = blockIdx.x * 256 + threadIdx.x;
    if (tid < SZW1) {
        int o = tid & (D_HID - 1), k = tid >> 8;          // o lane-minor
        float acc[NREL];
        #pragma unroll
        for (int r = 0; r < NREL; r++) acc[r] = 0.f;
        #pragma unroll
        for (int b = 0; b < NBASES; b++) {
            float bs = bases1[(b * D_IN + k) * D_HID + o];  // coalesced
            #pragma unroll
            for (int r = 0; r < NREL; r++) acc[r] += comp1[r * NBASES + b] * bs;
        }
        #pragma unroll
        for (int r = 0; r < NREL; r++)
            w1t[(r * D_HID + o) * D_IN + k] = f2b(acc[r]);
        w1t[(NREL * D_HID + o) * D_IN + k] = f2b(root1[k * D_HID + o]);  // coalesced read
    } else if (tid < SZW1 + SZW2) {
        int j = tid - SZW1;
        int o = j & (D_OUT - 1), k = j >> 6;
        float acc[NREL];
        #pragma unroll
        for (int r = 0; r < NREL; r++) acc[r] = 0.f;
        #pragma unroll
        for (int b = 0; b < NBASES; b++) {
            float bs = bases2[(b * D_HID + k) * D_OUT + o];  // coalesced
            #pragma unroll
            for (int r = 0; r < NREL; r++) acc[r] += comp2[r * NBASES + b] * bs;
        }
        #pragma unroll
        for (int r = 0; r < NREL; r++)
            w2t[(r * D_OUT + o) * D_HID + k] = f2b(acc[r]);
        w2t[(NREL * D_OUT + o) * D_HID + k] = f2b(root2[k * D_OUT + o]);
    } else if (tid < SZW1 + SZW2 + SZX) {
        int j = tid - SZW1 - SZW2;
        xbf[j] = f2b(x[j]);
    } else if (tid < SZW1 + SZW2 + SZX + NE) {
        int e = tid - SZW1 - SZW2 - SZX;
        atomicAdd(&deg[dst[e]], 1);
    }
}

// ---------- CSR build ----------
__global__ __launch_bounds__(256) void scan_blk(
    const int* __restrict__ deg, int* __restrict__ local, int* __restrict__ bsum)
{
    __shared__ int wsum[4];
    int tid = threadIdx.x, lane = tid & 63, w = tid >> 6;
    int i = blockIdx.x * 256 + tid;
    int v = (i < NN) ? deg[i] : 0;
    int x = v;
    #pragma unroll
    for (int d = 1; d < 64; d <<= 1) {
        int y = __shfl_up(x, d, 64);
        if (lane >= d) x += y;
    }
    if (lane == 63) wsum[w] = x;
    __syncthreads();
    int woff = 0;
    for (int j = 0; j < w; j++) woff += wsum[j];
    if (i < NN) local[i] = woff + x - v;
    if (tid == 255) bsum[blockIdx.x] = woff + x;
}

__global__ __launch_bounds__(256) void scan_fin(
    const int* __restrict__ local, const int* __restrict__ bsum,
    int* __restrict__ offs, int* __restrict__ cursor)
{
    __shared__ int boff_s[NBLK];
    int tid = threadIdx.x;
    if (tid < 64) {
        int carry = 0;
        for (int base = 0; base < NBLK; base += 64) {
            int i = base + tid;
            int v = (i < NBLK) ? bsum[i] : 0;
            int x = v;
            #pragma unroll
            for (int d = 1; d < 64; d <<= 1) {
                int y = __shfl_up(x, d, 64);
                if (tid >= d) x += y;
            }
            if (i < NBLK) boff_s[i] = carry + x - v;
            carry += __shfl(x, 63, 64);
        }
    }
    __syncthreads();
    int i = blockIdx.x * 256 + tid;
    if (i < NN) {
        int o = local[i] + boff_s[i >> 8];
        offs[i] = o;
        cursor[i] = o;
    }
    if (i == NN) offs[NN] = NE;
}

// ep1 = src*N1 + rel*D_HID; ep2 == ep1>>2 exactly, so no ep2 array.
__global__ __launch_bounds__(256) void scatter_ep(
    const int* __restrict__ src, const int* __restrict__ dst, const int* __restrict__ etype,
    int* __restrict__ cursor, int* __restrict__ ep1)
{
    int e = blockIdx.x * 256 + threadIdx.x;
    if (e >= NE) return;
    int d = dst[e];
    int s = src[e], r = etype[e];
    int pos = atomicAdd(&cursor[d], 1);
    ep1[pos] = s * N1 + r * D_HID;
}

// ---------- bf16 MFMA GEMM, DIRECT-FRAGMENT (no LDS, no barriers): C = A @ Bt^T ----------
// K is tiny (128/256) so LDS staging bought ~nothing and cost a barrier-drain
// per 16-MFMA chunk (4 chunks total for GEMM1). The 16x16x32 fragment is 8
// CONTIGUOUS k-elements per lane and both A and Bt are K-contiguous, so each
// lane loads its fragment straight from global as bf16x8:
//   af[mt][lane] = A [(row0+(wm*4+mt)*16+(lane&15))*K + c*32+(lane>>4)*8]
//   bf[nt][lane] = Bt[(col0+(wn*4+nt)*16+(lane&15))*K + c*32+(lane>>4)*8]
// (identical operand contents to the old LDS path -> epilogue unchanged).
// Register double-buffer across chunks; waves run free (no lockstep), B is
// L2-resident (655 KB / 320 KB), A rows read 2x per block from L2/HBM.
__global__ __launch_bounds__(256) void gemm_bf16(
    const ushort* __restrict__ A, const ushort* __restrict__ Bt, ushort* __restrict__ C,
    int M, int N, int K)
{
    int tid = threadIdx.x;
    int lane = tid & 63, w = tid >> 6;
    int wm = w >> 1, wn = w & 1;
    int row0 = blockIdx.y * 128, col0 = blockIdx.x * 128;

    int mr = lane & 15, kq = lane >> 4;
    int kof = kq * 8;

    // per-fragment base pointers (chunk 0)
    const ushort* pA[4];
    const ushort* pB[4];
    #pragma unroll
    for (int t = 0; t < 4; t++) {
        int ar = min(row0 + (wm * 4 + t) * 16 + mr, M - 1);
        pA[t] = &A[(size_t)ar * K + kof];
        int br = col0 + (wn * 4 + t) * 16 + mr;   // N is a multiple of 128
        pB[t] = &Bt[(size_t)br * K + kof];
    }

    f32x4 acc[4][4];
    #pragma unroll
    for (int mt = 0; mt < 4; mt++)
        #pragma unroll
        for (int nt = 0; nt < 4; nt++)
            acc[mt][nt] = (f32x4){0.f, 0.f, 0.f, 0.f};

    bf16x8 caf[4], cbf[4];
    #pragma unroll
    for (int t = 0; t < 4; t++) {
        caf[t] = *(const bf16x8*)pA[t];
        cbf[t] = *(const bf16x8*)pB[t];
    }

    const int NC = K >> 5;
    for (int c = 0; c < NC; c++) {
        bf16x8 naf[4], nbf[4];
        if (c + 1 < NC) {
            #pragma unroll
            for (int t = 0; t < 4; t++) {
                pA[t] += 32; pB[t] += 32;
                naf[t] = *(const bf16x8*)pA[t];
                nbf[t] = *(const bf16x8*)pB[t];
            }
        }
        #pragma unroll
        for (int mt = 0; mt < 4; mt++)
            #pragma unroll
            for (int nt = 0; nt < 4; nt++)
                acc[mt][nt] = __builtin_amdgcn_mfma_f32_16x16x32_bf16(
                    cbf[nt], caf[mt], acc[mt][nt], 0, 0, 0);
        #pragma unroll
        for (int t = 0; t < 4; t++) { caf[t] = naf[t]; cbf[t] = nbf[t]; }
    }

    int qo = lane >> 4, cm = lane & 15;
    #pragma unroll
    for (int mt = 0; mt < 4; mt++) {
        int gr = row0 + wm * 64 + mt * 16 + cm;
        if (gr < M) {
            #pragma unroll
            for (int nt = 0; nt < 4; nt++) {
                int gc = col0 + wn * 64 + nt * 16 + qo * 4;
                uint2 o;
                o.x = pack2bf(acc[mt][nt][0], acc[mt][nt][1]);
                o.y = pack2bf(acc[mt][nt][2], acc[mt][nt][3]);
                *(uint2*)&C[(size_t)gr * N + gc] = o;
            }
        }
    }
}

// ---------- gather1: max over in-edges + root + bias -> LN -> ReLU -> h (bf16) ----------
__global__ __launch_bounds__(256) void gather1(
    const ushort* __restrict__ xw1, const int* __restrict__ offs, const int* __restrict__ ep1,
    const float* __restrict__ bias, const float* __restrict__ g, const float* __restrict__ b,
    ushort* __restrict__ h)
{
    int n = blockIdx.x * 4 + (threadIdx.x >> 6);
    if (n >= NN) return;
    int lane = threadIdx.x & 63;
    int lane4 = lane * 4;
    int e0 = __builtin_amdgcn_readfirstlane(offs[n]);
    int e1 = __builtin_amdgcn_readfirstlane(offs[n + 1]);

    float m0 = -INFINITY, m1 = -INFINITY, m2 = -INFINITY, m3 = -INFINITY;
    int e = e0;
    for (; e + 8 <= e1; e += 8) {
        int p[8];
        #pragma unroll
        for (int j = 0; j < 8; j++) p[j] = ep1[e + j];
        ushort4 v[8];
        #pragma unroll
        for (int j = 0; j < 8; j++) v[j] = *(const ushort4*)&xw1[(size_t)(p[j] + lane4)];
        #pragma unroll
        for (int j = 0; j < 8; j++) {
            m0 = fmaxf(m0, b2f(v[j].x)); m1 = fmaxf(m1, b2f(v[j].y));
            m2 = fmaxf(m2, b2f(v[j].z)); m3 = fmaxf(m3, b2f(v[j].w));
        }
    }
    for (; e + 2 <= e1; e += 2) {
        int pa = ep1[e], pb = ep1[e + 1];
        ushort4 va = *(const ushort4*)&xw1[(size_t)(pa + lane4)];
        ushort4 vb = *(const ushort4*)&xw1[(size_t)(pb + lane4)];
        m0 = fmaxf(m0, fmaxf(b2f(va.x), b2f(vb.x)));
        m1 = fmaxf(m1, fmaxf(b2f(va.y), b2f(vb.y)));
        m2 = fmaxf(m2, fmaxf(b2f(va.z), b2f(vb.z)));
        m3 = fmaxf(m3, fmaxf(b2f(va.w), b2f(vb.w)));
    }
    for (; e < e1; e++) {
        int p = ep1[e];
        ushort4 v = *(const ushort4*)&xw1[(size_t)(p + lane4)];
        m0 = fmaxf(m0, b2f(v.x)); m1 = fmaxf(m1, b2f(v.y));
        m2 = fmaxf(m2, b2f(v.z)); m3 = fmaxf(m3, b2f(v.w));
    }
    if (e1 == e0) { m0 = m1 = m2 = m3 = 0.f; }

    ushort4 rt = *(const ushort4*)&xw1[(size_t)n * N1 + NREL * D_HID + lane4];
    int c = lane4;
    float t0 = m0 + b2f(rt.x) + bias[c + 0];
    float t1 = m1 + b2f(rt.y) + bias[c + 1];
    float t2 = m2 + b2f(rt.z) + bias[c + 2];
    float t3 = m3 + b2f(rt.w) + bias[c + 3];

    float s = t0 + t1 + t2 + t3;
    float s2 = t0 * t0 + t1 * t1 + t2 * t2 + t3 * t3;
    #pragma unroll
    for (int m = 32; m >= 1; m >>= 1) {
        s  += __shfl_xor(s,  m, 64);
        s2 += __shfl_xor(s2, m, 64);
    }
    float mu = s * (1.f / D_HID);
    float var = s2 * (1.f / D_HID) - mu * mu;
    float rs = rsqrtf(var + LN_EPS);

    ushort4 o;
    o.x = f2b(fmaxf((t0 - mu) * rs * g[c + 0] + b[c + 0], 0.f));
    o.y = f2b(fmaxf((t1 - mu) * rs * g[c + 1] + b[c + 1], 0.f));
    o.z = f2b(fmaxf((t2 - mu) * rs * g[c + 2] + b[c + 2], 0.f));
    o.w = f2b(fmaxf((t3 - mu) * rs * g[c + 3] + b[c + 3], 0.f));
    *(ushort4*)&h[(size_t)n * D_HID + c] = o;
}

// ---------- gather2: sum over in-edges + root + bias -> LN -> log_softmax -> out ----------
__global__ __launch_bounds__(256) void gather2(
    const ushort* __restrict__ xw2, const int* __restrict__ offs, const int* __restrict__ ep1,
    const float* __restrict__ bias, const float* __restrict__ g, const float* __restrict__ b,
    float* __restrict__ out)
{
    int n = blockIdx.x * 4 + (threadIdx.x >> 6);
    if (n >= NN) return;
    int lane = threadIdx.x & 63;
    int e0 = __builtin_amdgcn_readfirstlane(offs[n]);
    int e1 = __builtin_amdgcn_readfirstlane(offs[n + 1]);

    float s = 0.f;
    int e = e0;
    for (; e + 8 <= e1; e += 8) {
        int p[8];
        #pragma unroll
        for (int j = 0; j < 8; j++) p[j] = ep1[e + j] >> 2;
        float a[8];
        #pragma unroll
        for (int j = 0; j < 8; j++) a[j] = b2f(xw2[(size_t)(p[j] + lane)]);
        s += ((a[0] + a[1]) + (a[2] + a[3])) + ((a[4] + a[5]) + (a[6] + a[7]));
    }
    for (; e < e1; e++) {
        s += b2f(xw2[(size_t)((ep1[e] >> 2) + lane)]);
    }
    float v = s + b2f(xw2[(size_t)n * N2 + NREL * D_OUT + lane]) + bias[lane];

    float sm = v, s2 = v * v;
    #pragma unroll
    for (int m = 32; m >= 1; m >>= 1) {
        sm += __shfl_xor(sm, m, 64);
        s2 += __shfl_xor(s2, m, 64);
    }
    float mu = sm * (1.f / D_OUT);
    float var = s2 * (1.f / D_OUT) - mu * mu;
    float y = (v - mu) * rsqrtf(var + LN_EPS) * g[lane] + b[lane];

    float mx = y;
    #pragma unroll
    for (int m = 32; m >= 1; m >>= 1) mx = fmaxf(mx, __shfl_xor(mx, m, 64));
    float ex = __expf(y - mx);
    float se = ex;
    #pragma unroll
    for (int m = 32; m >= 1; m >>= 1) se += __shfl_xor(se, m, 64);
    out[(size_t)n * D_OUT + lane] = y - mx - logf(se);
}

extern "C" void kernel_launch(void* const* d_in, const int* in_sizes, int n_in,
                              void* d_out, int out_size, void* d_ws, size_t ws_size,
                              hipStream_t stream)
{
    const float* x      = (const float*)d_in[0];
    const int*   eidx   = (const int*)  d_in[1];
    const int*   etype  = (const int*)  d_in[2];
    const float* bases1 = (const float*)d_in[3];
    const float* comp1  = (const float*)d_in[4];
    const float* root1  = (const float*)d_in[5];
    const float* bias1  = (const float*)d_in[6];
    const float* g1     = (const float*)d_in[7];
    const float* b1     = (const float*)d_in[8];
    const float* bases2 = (const float*)d_in[9];
    const float* comp2  = (const float*)d_in[10];
    const float* root2  = (const float*)d_in[11];
    const float* bias2  = (const float*)d_in[12];
    const float* g2     = (const float*)d_in[13];
    const float* b2     = (const float*)d_in[14];

    const int* src = eidx;
    const int* dst = eidx + NE;

    char* p = (char*)d_ws;
    auto alloc = [&](size_t bytes) -> char* {
        char* r = p;
        p += (bytes + 255) & ~(size_t)255;
        return r;
    };
    ushort* xbf    = (ushort*)alloc((size_t)NN * D_IN * 2);
    ushort* w1t    = (ushort*)alloc((size_t)N1 * D_IN * 2);
    ushort* w2t    = (ushort*)alloc((size_t)N2 * D_HID * 2);
    ushort* xw1    = (ushort*)alloc((size_t)NN * N1 * 2);
    ushort* xw2    = (ushort*)alloc((size_t)NN * N2 * 2);
    ushort* h      = (ushort*)alloc((size_t)NN * D_HID * 2);
    int*    deg    = (int*)   alloc((size_t)NN * 4);
    int*    local  = (int*)   alloc((size_t)NN * 4);
    int*    bsum   = (int*)   alloc((size_t)NBLK * 4);
    int*    offs   = (int*)   alloc((size_t)(NN + 1) * 4);
    int*    cursor = (int*)   alloc((size_t)NN * 4);
    int*    ep1    = (int*)   alloc((size_t)NE * 4);

    hipMemsetAsync(deg, 0, (size_t)NN * 4, stream);
    const int SZP = D_IN * D_HID + D_HID * D_OUT + NN * D_IN + NE;
    prep_all<<<(SZP + 255) / 256, 256, 0, stream>>>(
        bases1, comp1, root1, bases2, comp2, root2, x, dst, w1t, w2t, xbf, deg);

    scan_blk<<<NBLK, 256, 0, stream>>>(deg, local, bsum);
    scan_fin<<<NBLK, 256, 0, stream>>>(local, bsum, offs, cursor);
    scatter_ep<<<(NE + 255) / 256, 256, 0, stream>>>(src, dst, etype, cursor, ep1);

    gemm_bf16<<<dim3(N1 / 128, (NN + 127) / 128), 256, 0, stream>>>(xbf, w1t, xw1, NN, N1, D_IN);
    gather1<<<(NN + 3) / 4, 256, 0, stream>>>(xw1, offs, ep1, bias1, g1, b1, h);

    gemm_bf16<<<dim3(N2 / 128, (NN + 127) / 128), 256, 0, stream>>>(h, w2t, xw2, NN, N2, D_HID);
    gather2<<<(NN + 3) / 4, 256, 0, stream>>>(xw2, offs, ep1, bias2, g2, b2, (float*)d_out);
}

// Round 3
// 261.874 us; speedup vs baseline: 1.0556x; 1.0556x over previous
//
#include <hip/hip_runtime.h>
#include <math.h>

#define NN 20000
#define NE 320000
#define NREL 9
#define NBASES 9
#define D_IN 128
#define D_HID 256
#define D_OUT 64
#define LN_EPS 1e-5f

#define N1 (NREL * D_HID + D_HID)   // 2560
#define N2 (NREL * D_OUT + D_OUT)   // 640
#define NBLK ((NN + 255) / 256)     // 79

typedef __attribute__((ext_vector_type(8))) short bf16x8;
typedef __attribute__((ext_vector_type(4))) float f32x4;

__device__ inline ushort f2b(float f) {
    unsigned u = __float_as_uint(f);
    return (ushort)((u + 0x7FFFu + ((u >> 16) & 1u)) >> 16);
}
__device__ inline float b2f(ushort h) { return __uint_as_float(((unsigned)h) << 16); }
__device__ inline unsigned pack2bf(float f0, float f1) {
    return (unsigned)f2b(f0) | ((unsigned)f2b(f1) << 16);
}

// ---------- fused prep: weights (coalesced basis reads) + x cast + dst histogram ----------
__global__ __launch_bounds__(256) void prep_all(
    const float* __restrict__ bases1, const float* __restrict__ comp1, const float* __restrict__ root1,
    const float* __restrict__ bases2, const float* __restrict__ comp2, const float* __restrict__ root2,
    const float* __restrict__ x, const int* __restrict__ dst,
    ushort* __restrict__ w1t, ushort* __restrict__ w2t, ushort* __restrict__ xbf,
    int* __restrict__ deg)
{
    const int SZW1 = D_IN * D_HID;   // 32768
    const int SZW2 = D_HID * D_OUT;  // 16384
    const int SZX  = NN * D_IN;      // 2560000
    int tid = blockIdx.x * 256 + threadIdx.x;
    if (tid < SZW1) {
        int o = tid & (D_HID - 1), k = tid >> 8;          // o lane-minor
        float acc[NREL];
        #pragma unroll
        for (int r = 0; r < NREL; r++) acc[r] = 0.f;
        #pragma unroll
        for (int b = 0; b < NBASES; b++) {
            float bs = bases1[(b * D_IN + k) * D_HID + o];  // coalesced
            #pragma unroll
            for (int r = 0; r < NREL; r++) acc[r] += comp1[r * NBASES + b] * bs;
        }
        #pragma unroll
        for (int r = 0; r < NREL; r++)
            w1t[(r * D_HID + o) * D_IN + k] = f2b(acc[r]);
        w1t[(NREL * D_HID + o) * D_IN + k] = f2b(root1[k * D_HID + o]);  // coalesced read
    } else if (tid < SZW1 + SZW2) {
        int j = tid - SZW1;
        int o = j & (D_OUT - 1), k = j >> 6;
        float acc[NREL];
        #pragma unroll
        for (int r = 0; r < NREL; r++) acc[r] = 0.f;
        #pragma unroll
        for (int b = 0; b < NBASES; b++) {
            float bs = bases2[(b * D_HID + k) * D_OUT + o];  // coalesced
            #pragma unroll
            for (int r = 0; r < NREL; r++) acc[r] += comp2[r * NBASES + b] * bs;
        }
        #pragma unroll
        for (int r = 0; r < NREL; r++)
            w2t[(r * D_OUT + o) * D_HID + k] = f2b(acc[r]);
        w2t[(NREL * D_OUT + o) * D_HID + k] = f2b(root2[k * D_OUT + o]);
    } else if (tid < SZW1 + SZW2 + SZX) {
        int j = tid - SZW1 - SZW2;
        xbf[j] = f2b(x[j]);
    } else if (tid < SZW1 + SZW2 + SZX + NE) {
        int e = tid - SZW1 - SZW2 - SZX;
        atomicAdd(&deg[dst[e]], 1);
    }
}

// ---------- CSR build ----------
__global__ __launch_bounds__(256) void scan_blk(
    const int* __restrict__ deg, int* __restrict__ local, int* __restrict__ bsum)
{
    __shared__ int wsum[4];
    int tid = threadIdx.x, lane = tid & 63, w = tid >> 6;
    int i = blockIdx.x * 256 + tid;
    int v = (i < NN) ? deg[i] : 0;
    int x = v;
    #pragma unroll
    for (int d = 1; d < 64; d <<= 1) {
        int y = __shfl_up(x, d, 64);
        if (lane >= d) x += y;
    }
    if (lane == 63) wsum[w] = x;
    __syncthreads();
    int woff = 0;
    for (int j = 0; j < w; j++) woff += wsum[j];
    if (i < NN) local[i] = woff + x - v;
    if (tid == 255) bsum[blockIdx.x] = woff + x;
}

__global__ __launch_bounds__(256) void scan_fin(
    const int* __restrict__ local, const int* __restrict__ bsum,
    int* __restrict__ offs, int* __restrict__ cursor)
{
    __shared__ int boff_s[NBLK];
    int tid = threadIdx.x;
    if (tid < 64) {
        int carry = 0;
        for (int base = 0; base < NBLK; base += 64) {
            int i = base + tid;
            int v = (i < NBLK) ? bsum[i] : 0;
            int x = v;
            #pragma unroll
            for (int d = 1; d < 64; d <<= 1) {
                int y = __shfl_up(x, d, 64);
                if (tid >= d) x += y;
            }
            if (i < NBLK) boff_s[i] = carry + x - v;
            carry += __shfl(x, 63, 64);
        }
    }
    __syncthreads();
    int i = blockIdx.x * 256 + tid;
    if (i < NN) {
        int o = local[i] + boff_s[i >> 8];
        offs[i] = o;
        cursor[i] = o;
    }
    if (i == NN) offs[NN] = NE;
}

// ep1 = src*N1 + rel*D_HID; ep2 == ep1>>2 exactly, so no ep2 array.
__global__ __launch_bounds__(256) void scatter_ep(
    const int* __restrict__ src, const int* __restrict__ dst, const int* __restrict__ etype,
    int* __restrict__ cursor, int* __restrict__ ep1)
{
    int e = blockIdx.x * 256 + threadIdx.x;
    if (e >= NE) return;
    int d = dst[e];
    int s = src[e], r = etype[e];
    int pos = atomicAdd(&cursor[d], 1);
    ep1[pos] = s * N1 + r * D_HID;
}

// ---------- bf16 MFMA GEMM (occupancy retile): C = A @ Bt^T ----------
// r9 machinery (reg-staging double-buffered LDS, swizzled slots, operand-
// swapped MFMA) but tile = 128x64, wave = 32x64 -> acc 2x4 = 32 AGPRs
// (was 4x4 = 64). Total regs ~100 -> ~5 waves/SIMD resident (was 3), LDS
// 24 KB (was 32). Independent blocks at different phases hide the barrier
// drains that pinned r9 at 25% occupancy / 10% MfmaUtil.
__global__ __launch_bounds__(256) void gemm_bf16(
    const ushort* __restrict__ A, const ushort* __restrict__ Bt, ushort* __restrict__ C,
    int M, int N, int K)
{
    __shared__ ushort As[2][512 * 8];   // 128 rows x 4 kq slots, 8 KB/buf
    __shared__ ushort Bs[2][256 * 8];   // 64 cols  x 4 kq slots, 4 KB/buf

    int tid = threadIdx.x;
    int lane = tid & 63, w = tid >> 6;          // w = wave's row-block 0..3
    int row0 = blockIdx.y * 128, col0 = blockIdx.x * 64;

    // staging: LDS slot tid holds row g*16+((swr-2q)&15), k-quarter q
    int g = tid >> 6, q = (tid >> 4) & 3, swr = tid & 15;
    int mrw = (swr - 2 * q) & 15;
    int arow = g * 16 + mrw;                    // 0..63
    const ushort* gA0 = &A[(size_t)min(row0 + arow, M - 1) * K + q * 8];
    const ushort* gA1 = &A[(size_t)min(row0 + arow + 64, M - 1) * K + q * 8];
    const ushort* gB0 = &Bt[(size_t)(col0 + arow) * K + q * 8];
    int lo  = tid * 8;
    int lo1 = (256 + tid) * 8;

    int mr = lane & 15, kq = lane >> 4;
    int inner = (kq * 16 + ((mr + 2 * kq) & 15)) * 8;

    f32x4 acc[2][4];
    #pragma unroll
    for (int mt = 0; mt < 2; mt++)
        #pragma unroll
        for (int nt = 0; nt < 4; nt++)
            acc[mt][nt] = (f32x4){0.f, 0.f, 0.f, 0.f};

    {
        bf16x8 a0 = *(const bf16x8*)gA0;
        bf16x8 a1 = *(const bf16x8*)gA1;
        bf16x8 b0 = *(const bf16x8*)gB0;
        *(bf16x8*)&As[0][lo]  = a0;
        *(bf16x8*)&As[0][lo1] = a1;
        *(bf16x8*)&Bs[0][lo]  = b0;
    }

    const int NC = K >> 5;
    for (int c = 0; c < NC; c++) {
        __syncthreads();
        int cur = c & 1, nxt = cur ^ 1;
        bf16x8 a0, a1, b0;
        bool more = (c + 1 < NC);
        if (more) {
            gA0 += 32; gA1 += 32; gB0 += 32;
            a0 = *(const bf16x8*)gA0;
            a1 = *(const bf16x8*)gA1;
            b0 = *(const bf16x8*)gB0;
        }

        bf16x8 af[2], bfr[4];
        #pragma unroll
        for (int mt = 0; mt < 2; mt++)
            af[mt] = *(const bf16x8*)&As[cur][(size_t)((w * 2 + mt) * 64) * 8 + inner];
        #pragma unroll
        for (int nt = 0; nt < 4; nt++)
            bfr[nt] = *(const bf16x8*)&Bs[cur][(size_t)(nt * 64) * 8 + inner];
        #pragma unroll
        for (int mt = 0; mt < 2; mt++)
            #pragma unroll
            for (int nt = 0; nt < 4; nt++)
                acc[mt][nt] = __builtin_amdgcn_mfma_f32_16x16x32_bf16(
                    bfr[nt], af[mt], acc[mt][nt], 0, 0, 0);

        if (more) {
            *(bf16x8*)&As[nxt][lo]  = a0;
            *(bf16x8*)&As[nxt][lo1] = a1;
            *(bf16x8*)&Bs[nxt][lo]  = b0;
        }
    }

    int qo = lane >> 4, cm = lane & 15;
    #pragma unroll
    for (int mt = 0; mt < 2; mt++) {
        int gr = row0 + w * 32 + mt * 16 + cm;
        if (gr < M) {
            #pragma unroll
            for (int nt = 0; nt < 4; nt++) {
                int gc = col0 + nt * 16 + qo * 4;
                uint2 o;
                o.x = pack2bf(acc[mt][nt][0], acc[mt][nt][1]);
                o.y = pack2bf(acc[mt][nt][2], acc[mt][nt][3]);
                *(uint2*)&C[(size_t)gr * N + gc] = o;
            }
        }
    }
}

// ---------- gather1: max over in-edges + root + bias -> LN -> ReLU -> h (bf16) ----------
__global__ __launch_bounds__(256) void gather1(
    const ushort* __restrict__ xw1, const int* __restrict__ offs, const int* __restrict__ ep1,
    const float* __restrict__ bias, const float* __restrict__ g, const float* __restrict__ b,
    ushort* __restrict__ h)
{
    int n = blockIdx.x * 4 + (threadIdx.x >> 6);
    if (n >= NN) return;
    int lane = threadIdx.x & 63;
    int lane4 = lane * 4;
    int e0 = __builtin_amdgcn_readfirstlane(offs[n]);
    int e1 = __builtin_amdgcn_readfirstlane(offs[n + 1]);

    float m0 = -INFINITY, m1 = -INFINITY, m2 = -INFINITY, m3 = -INFINITY;
    int e = e0;
    for (; e + 8 <= e1; e += 8) {
        int p[8];
        #pragma unroll
        for (int j = 0; j < 8; j++) p[j] = ep1[e + j];
        ushort4 v[8];
        #pragma unroll
        for (int j = 0; j < 8; j++) v[j] = *(const ushort4*)&xw1[(size_t)(p[j] + lane4)];
        #pragma unroll
        for (int j = 0; j < 8; j++) {
            m0 = fmaxf(m0, b2f(v[j].x)); m1 = fmaxf(m1, b2f(v[j].y));
            m2 = fmaxf(m2, b2f(v[j].z)); m3 = fmaxf(m3, b2f(v[j].w));
        }
    }
    for (; e + 2 <= e1; e += 2) {
        int pa = ep1[e], pb = ep1[e + 1];
        ushort4 va = *(const ushort4*)&xw1[(size_t)(pa + lane4)];
        ushort4 vb = *(const ushort4*)&xw1[(size_t)(pb + lane4)];
        m0 = fmaxf(m0, fmaxf(b2f(va.x), b2f(vb.x)));
        m1 = fmaxf(m1, fmaxf(b2f(va.y), b2f(vb.y)));
        m2 = fmaxf(m2, fmaxf(b2f(va.z), b2f(vb.z)));
        m3 = fmaxf(m3, fmaxf(b2f(va.w), b2f(vb.w)));
    }
    for (; e < e1; e++) {
        int p = ep1[e];
        ushort4 v = *(const ushort4*)&xw1[(size_t)(p + lane4)];
        m0 = fmaxf(m0, b2f(v.x)); m1 = fmaxf(m1, b2f(v.y));
        m2 = fmaxf(m2, b2f(v.z)); m3 = fmaxf(m3, b2f(v.w));
    }
    if (e1 == e0) { m0 = m1 = m2 = m3 = 0.f; }

    ushort4 rt = *(const ushort4*)&xw1[(size_t)n * N1 + NREL * D_HID + lane4];
    int c = lane4;
    float t0 = m0 + b2f(rt.x) + bias[c + 0];
    float t1 = m1 + b2f(rt.y) + bias[c + 1];
    float t2 = m2 + b2f(rt.z) + bias[c + 2];
    float t3 = m3 + b2f(rt.w) + bias[c + 3];

    float s = t0 + t1 + t2 + t3;
    float s2 = t0 * t0 + t1 * t1 + t2 * t2 + t3 * t3;
    #pragma unroll
    for (int m = 32; m >= 1; m >>= 1) {
        s  += __shfl_xor(s,  m, 64);
        s2 += __shfl_xor(s2, m, 64);
    }
    float mu = s * (1.f / D_HID);
    float var = s2 * (1.f / D_HID) - mu * mu;
    float rs = rsqrtf(var + LN_EPS);

    ushort4 o;
    o.x = f2b(fmaxf((t0 - mu) * rs * g[c + 0] + b[c + 0], 0.f));
    o.y = f2b(fmaxf((t1 - mu) * rs * g[c + 1] + b[c + 1], 0.f));
    o.z = f2b(fmaxf((t2 - mu) * rs * g[c + 2] + b[c + 2], 0.f));
    o.w = f2b(fmaxf((t3 - mu) * rs * g[c + 3] + b[c + 3], 0.f));
    *(ushort4*)&h[(size_t)n * D_HID + c] = o;
}

// ---------- gather2: sum over in-edges + root + bias -> LN -> log_softmax -> out ----------
__global__ __launch_bounds__(256) void gather2(
    const ushort* __restrict__ xw2, const int* __restrict__ offs, const int* __restrict__ ep1,
    const float* __restrict__ bias, const float* __restrict__ g, const float* __restrict__ b,
    float* __restrict__ out)
{
    int n = blockIdx.x * 4 + (threadIdx.x >> 6);
    if (n >= NN) return;
    int lane = threadIdx.x & 63;
    int e0 = __builtin_amdgcn_readfirstlane(offs[n]);
    int e1 = __builtin_amdgcn_readfirstlane(offs[n + 1]);

    float s = 0.f;
    int e = e0;
    for (; e + 8 <= e1; e += 8) {
        int p[8];
        #pragma unroll
        for (int j = 0; j < 8; j++) p[j] = ep1[e + j] >> 2;
        float a[8];
        #pragma unroll
        for (int j = 0; j < 8; j++) a[j] = b2f(xw2[(size_t)(p[j] + lane)]);
        s += ((a[0] + a[1]) + (a[2] + a[3])) + ((a[4] + a[5]) + (a[6] + a[7]));
    }
    for (; e < e1; e++) {
        s += b2f(xw2[(size_t)((ep1[e] >> 2) + lane)]);
    }
    float v = s + b2f(xw2[(size_t)n * N2 + NREL * D_OUT + lane]) + bias[lane];

    float sm = v, s2 = v * v;
    #pragma unroll
    for (int m = 32; m >= 1; m >>= 1) {
        sm += __shfl_xor(sm, m, 64);
        s2 += __shfl_xor(s2, m, 64);
    }
    float mu = sm * (1.f / D_OUT);
    float var = s2 * (1.f / D_OUT) - mu * mu;
    float y = (v - mu) * rsqrtf(var + LN_EPS) * g[lane] + b[lane];

    float mx = y;
    #pragma unroll
    for (int m = 32; m >= 1; m >>= 1) mx = fmaxf(mx, __shfl_xor(mx, m, 64));
    float ex = __expf(y - mx);
    float se = ex;
    #pragma unroll
    for (int m = 32; m >= 1; m >>= 1) se += __shfl_xor(se, m, 64);
    out[(size_t)n * D_OUT + lane] = y - mx - logf(se);
}

extern "C" void kernel_launch(void* const* d_in, const int* in_sizes, int n_in,
                              void* d_out, int out_size, void* d_ws, size_t ws_size,
                              hipStream_t stream)
{
    const float* x      = (const float*)d_in[0];
    const int*   eidx   = (const int*)  d_in[1];
    const int*   etype  = (const int*)  d_in[2];
    const float* bases1 = (const float*)d_in[3];
    const float* comp1  = (const float*)d_in[4];
    const float* root1  = (const float*)d_in[5];
    const float* bias1  = (const float*)d_in[6];
    const float* g1     = (const float*)d_in[7];
    const float* b1     = (const float*)d_in[8];
    const float* bases2 = (const float*)d_in[9];
    const float* comp2  = (const float*)d_in[10];
    const float* root2  = (const float*)d_in[11];
    const float* bias2  = (const float*)d_in[12];
    const float* g2     = (const float*)d_in[13];
    const float* b2     = (const float*)d_in[14];

    const int* src = eidx;
    const int* dst = eidx + NE;

    char* p = (char*)d_ws;
    auto alloc = [&](size_t bytes) -> char* {
        char* r = p;
        p += (bytes + 255) & ~(size_t)255;
        return r;
    };
    ushort* xbf    = (ushort*)alloc((size_t)NN * D_IN * 2);
    ushort* w1t    = (ushort*)alloc((size_t)N1 * D_IN * 2);
    ushort* w2t    = (ushort*)alloc((size_t)N2 * D_HID * 2);
    ushort* xw1    = (ushort*)alloc((size_t)NN * N1 * 2);
    ushort* xw2    = (ushort*)alloc((size_t)NN * N2 * 2);
    ushort* h      = (ushort*)alloc((size_t)NN * D_HID * 2);
    int*    deg    = (int*)   alloc((size_t)NN * 4);
    int*    local  = (int*)   alloc((size_t)NN * 4);
    int*    bsum   = (int*)   alloc((size_t)NBLK * 4);
    int*    offs   = (int*)   alloc((size_t)(NN + 1) * 4);
    int*    cursor = (int*)   alloc((size_t)NN * 4);
    int*    ep1    = (int*)   alloc((size_t)NE * 4);

    hipMemsetAsync(deg, 0, (size_t)NN * 4, stream);
    const int SZP = D_IN * D_HID + D_HID * D_OUT + NN * D_IN + NE;
    prep_all<<<(SZP + 255) / 256, 256, 0, stream>>>(
        bases1, comp1, root1, bases2, comp2, root2, x, dst, w1t, w2t, xbf, deg);

    scan_blk<<<NBLK, 256, 0, stream>>>(deg, local, bsum);
    scan_fin<<<NBLK, 256, 0, stream>>>(local, bsum, offs, cursor);
    scatter_ep<<<(NE + 255) / 256, 256, 0, stream>>>(src, dst, etype, cursor, ep1);

    gemm_bf16<<<dim3(N1 / 64, (NN + 127) / 128), 256, 0, stream>>>(xbf, w1t, xw1, NN, N1, D_IN);
    gather1<<<(NN + 3) / 4, 256, 0, stream>>>(xw1, offs, ep1, bias1, g1, b1, h);

    gemm_bf16<<<dim3(N2 / 64, (NN + 127) / 128), 256, 0, stream>>>(h, w2t, xw2, NN, N2, D_HID);
    gather2<<<(NN + 3) / 4, 256, 0, stream>>>(xw2, offs, ep1, bias2, g2, b2, (float*)d_out);
}

// Round 4
// 225.541 us; speedup vs baseline: 1.2256x; 1.1611x over previous
//
#include <hip/hip_runtime.h>
#include <math.h>

#define NN 20000
#define NE 320000
#define NREL 9
#define NBASES 9
#define D_IN 128
#define D_HID 256
#define D_OUT 64
#define LN_EPS 1e-5f

#define N1 (NREL * D_HID + D_HID)   // 2560
#define N2 (NREL * D_OUT + D_OUT)   // 640
#define NBLK ((NN + 255) / 256)     // 79

typedef __attribute__((ext_vector_type(8))) short bf16x8;
typedef __attribute__((ext_vector_type(4))) float f32x4;

__device__ inline ushort f2b(float f) {
    unsigned u = __float_as_uint(f);
    return (ushort)((u + 0x7FFFu + ((u >> 16) & 1u)) >> 16);
}
__device__ inline float b2f(ushort h) { return __uint_as_float(((unsigned)h) << 16); }
__device__ inline unsigned pack2bf(float f0, float f1) {
    return (unsigned)f2b(f0) | ((unsigned)f2b(f1) << 16);
}

// ---------- fused prep: weights (coalesced basis reads) + x cast + dst histogram ----------
__global__ __launch_bounds__(256) void prep_all(
    const float* __restrict__ bases1, const float* __restrict__ comp1, const float* __restrict__ root1,
    const float* __restrict__ bases2, const float* __restrict__ comp2, const float* __restrict__ root2,
    const float* __restrict__ x, const int* __restrict__ dst,
    ushort* __restrict__ w1t, ushort* __restrict__ w2t, ushort* __restrict__ xbf,
    int* __restrict__ deg)
{
    const int SZW1 = D_IN * D_HID;   // 32768
    const int SZW2 = D_HID * D_OUT;  // 16384
    const int SZX  = NN * D_IN;      // 2560000
    int tid = blockIdx.x * 256 + threadIdx.x;
    if (tid < SZW1) {
        int o = tid & (D_HID - 1), k = tid >> 8;          // o lane-minor
        float acc[NREL];
        #pragma unroll
        for (int r = 0; r < NREL; r++) acc[r] = 0.f;
        #pragma unroll
        for (int b = 0; b < NBASES; b++) {
            float bs = bases1[(b * D_IN + k) * D_HID + o];  // coalesced
            #pragma unroll
            for (int r = 0; r < NREL; r++) acc[r] += comp1[r * NBASES + b] * bs;
        }
        #pragma unroll
        for (int r = 0; r < NREL; r++)
            w1t[(r * D_HID + o) * D_IN + k] = f2b(acc[r]);
        w1t[(NREL * D_HID + o) * D_IN + k] = f2b(root1[k * D_HID + o]);  // coalesced read
    } else if (tid < SZW1 + SZW2) {
        int j = tid - SZW1;
        int o = j & (D_OUT - 1), k = j >> 6;
        float acc[NREL];
        #pragma unroll
        for (int r = 0; r < NREL; r++) acc[r] = 0.f;
        #pragma unroll
        for (int b = 0; b < NBASES; b++) {
            float bs = bases2[(b * D_HID + k) * D_OUT + o];  // coalesced
            #pragma unroll
            for (int r = 0; r < NREL; r++) acc[r] += comp2[r * NBASES + b] * bs;
        }
        #pragma unroll
        for (int r = 0; r < NREL; r++)
            w2t[(r * D_OUT + o) * D_HID + k] = f2b(acc[r]);
        w2t[(NREL * D_OUT + o) * D_HID + k] = f2b(root2[k * D_OUT + o]);
    } else if (tid < SZW1 + SZW2 + SZX) {
        int j = tid - SZW1 - SZW2;
        xbf[j] = f2b(x[j]);
    } else if (tid < SZW1 + SZW2 + SZX + NE) {
        int e = tid - SZW1 - SZW2 - SZX;
        atomicAdd(&deg[dst[e]], 1);
    }
}

// ---------- CSR build ----------
__global__ __launch_bounds__(256) void scan_blk(
    const int* __restrict__ deg, int* __restrict__ local, int* __restrict__ bsum)
{
    __shared__ int wsum[4];
    int tid = threadIdx.x, lane = tid & 63, w = tid >> 6;
    int i = blockIdx.x * 256 + tid;
    int v = (i < NN) ? deg[i] : 0;
    int x = v;
    #pragma unroll
    for (int d = 1; d < 64; d <<= 1) {
        int y = __shfl_up(x, d, 64);
        if (lane >= d) x += y;
    }
    if (lane == 63) wsum[w] = x;
    __syncthreads();
    int woff = 0;
    for (int j = 0; j < w; j++) woff += wsum[j];
    if (i < NN) local[i] = woff + x - v;
    if (tid == 255) bsum[blockIdx.x] = woff + x;
}

__global__ __launch_bounds__(256) void scan_fin(
    const int* __restrict__ local, const int* __restrict__ bsum,
    int* __restrict__ offs, int* __restrict__ cursor)
{
    __shared__ int boff_s[NBLK];
    int tid = threadIdx.x;
    if (tid < 64) {
        int carry = 0;
        for (int base = 0; base < NBLK; base += 64) {
            int i = base + tid;
            int v = (i < NBLK) ? bsum[i] : 0;
            int x = v;
            #pragma unroll
            for (int d = 1; d < 64; d <<= 1) {
                int y = __shfl_up(x, d, 64);
                if (tid >= d) x += y;
            }
            if (i < NBLK) boff_s[i] = carry + x - v;
            carry += __shfl(x, 63, 64);
        }
    }
    __syncthreads();
    int i = blockIdx.x * 256 + tid;
    if (i < NN) {
        int o = local[i] + boff_s[i >> 8];
        offs[i] = o;
        cursor[i] = o;
    }
    if (i == NN) offs[NN] = NE;
}

// ep1 = src*N1 + rel*D_HID; ep2 == ep1>>2 exactly, so no ep2 array.
__global__ __launch_bounds__(256) void scatter_ep(
    const int* __restrict__ src, const int* __restrict__ dst, const int* __restrict__ etype,
    int* __restrict__ cursor, int* __restrict__ ep1)
{
    int e = blockIdx.x * 256 + threadIdx.x;
    if (e >= NE) return;
    int d = dst[e];
    int s = src[e], r = etype[e];
    int pos = atomicAdd(&cursor[d], 1);
    ep1[pos] = s * N1 + r * D_HID;
}

// ---------- bf16 MFMA GEMM (r0 structure + coalesced epilogue): C = A @ Bt^T ----------
// Main loop identical to the 48us r9/r0 config: 128x128 tile, BK=32, double-
// buffered LDS, VGPR reg-staging, swizzled LDS slots, operand-swapped MFMA.
// NEW: epilogue stages the 128x128 bf16 C-tile in LDS (XOR-swizzled, ~2-way
// conflicts = free) and stores with fully-coalesced uint4: each wave writes
// 4 rows x 256B contiguous, replacing 16 scattered 8B stores per lane (16
// partial 32B L2 write transactions per wave-store) with 8 full-line ones.
__global__ __launch_bounds__(256) void gemm_bf16(
    const ushort* __restrict__ A, const ushort* __restrict__ Bt, ushort* __restrict__ C,
    int M, int N, int K)
{
    __shared__ ushort smem[16384];  // As[2][4096] | Bs[2][4096]; epilogue reuses all 32KB

    ushort* Asb = smem;             // As[buf] = Asb + buf*4096
    ushort* Bsb = smem + 8192;      // Bs[buf] = Bsb + buf*4096

    int tid = threadIdx.x;
    int lane = tid & 63, w = tid >> 6;
    int wm = w >> 1, wn = w & 1;
    int row0 = blockIdx.y * 128, col0 = blockIdx.x * 128;

    int r0 = tid >> 2, q0 = tid & 3;
    int mrw = r0 & 15, gw = r0 >> 4;
    int sw = q0 * 16 + ((mrw + 2 * q0) & 15);
    int lo0 = (gw * 64 + sw) * 8;
    int lo1 = ((gw + 4) * 64 + sw) * 8;
    int arow0 = min(row0 + r0, M - 1);
    int arow1 = min(row0 + r0 + 64, M - 1);
    const ushort* gA0 = &A[(size_t)arow0 * K + q0 * 8];
    const ushort* gA1 = &A[(size_t)arow1 * K + q0 * 8];
    const ushort* gB0 = &Bt[(size_t)(col0 + r0) * K + q0 * 8];
    const ushort* gB1 = &Bt[(size_t)(col0 + r0 + 64) * K + q0 * 8];

    int mr = lane & 15, kq = lane >> 4;
    int inner = (kq * 16 + ((mr + 2 * kq) & 15)) * 8;

    f32x4 acc[4][4];
    #pragma unroll
    for (int mt = 0; mt < 4; mt++)
        #pragma unroll
        for (int nt = 0; nt < 4; nt++)
            acc[mt][nt] = (f32x4){0.f, 0.f, 0.f, 0.f};

    {
        bf16x8 a0 = *(const bf16x8*)gA0;
        bf16x8 a1 = *(const bf16x8*)gA1;
        bf16x8 b0 = *(const bf16x8*)gB0;
        bf16x8 b1 = *(const bf16x8*)gB1;
        *(bf16x8*)&Asb[lo0] = a0;
        *(bf16x8*)&Asb[lo1] = a1;
        *(bf16x8*)&Bsb[lo0] = b0;
        *(bf16x8*)&Bsb[lo1] = b1;
    }

    const int NC = K >> 5;
    for (int c = 0; c < NC; c++) {
        __syncthreads();
        int cur = c & 1, nxt = cur ^ 1;
        bf16x8 a0, a1, b0, b1;
        bool more = (c + 1 < NC);
        if (more) {
            gA0 += 32; gA1 += 32; gB0 += 32; gB1 += 32;
            a0 = *(const bf16x8*)gA0;
            a1 = *(const bf16x8*)gA1;
            b0 = *(const bf16x8*)gB0;
            b1 = *(const bf16x8*)gB1;
        }

        bf16x8 af[4], bfr[4];
        #pragma unroll
        for (int mt = 0; mt < 4; mt++)
            af[mt] = *(const bf16x8*)&Asb[cur * 4096 + ((wm * 4 + mt) * 64) * 8 + inner];
        #pragma unroll
        for (int nt = 0; nt < 4; nt++)
            bfr[nt] = *(const bf16x8*)&Bsb[cur * 4096 + ((wn * 4 + nt) * 64) * 8 + inner];
        #pragma unroll
        for (int mt = 0; mt < 4; mt++)
            #pragma unroll
            for (int nt = 0; nt < 4; nt++)
                acc[mt][nt] = __builtin_amdgcn_mfma_f32_16x16x32_bf16(
                    bfr[nt], af[mt], acc[mt][nt], 0, 0, 0);

        if (more) {
            *(bf16x8*)&Asb[nxt * 4096 + lo0] = a0;
            *(bf16x8*)&Asb[nxt * 4096 + lo1] = a1;
            *(bf16x8*)&Bsb[nxt * 4096 + lo0] = b0;
            *(bf16x8*)&Bsb[nxt * 4096 + lo1] = b1;
        }
    }

    // ---- epilogue: acc -> LDS tile (XOR-swizzled) -> coalesced uint4 stores ----
    __syncthreads();                  // all waves done reading As/Bs
    int qo = lane >> 4, cm = lane & 15;
    #pragma unroll
    for (int mt = 0; mt < 4; mt++) {
        int row = wm * 64 + mt * 16 + cm;
        int sx = (row & 7) << 3;      // XOR in ushort units (16B granularity)
        #pragma unroll
        for (int nt = 0; nt < 4; nt++) {
            int colT = wn * 64 + nt * 16 + qo * 4;
            uint2 o;
            o.x = pack2bf(acc[mt][nt][0], acc[mt][nt][1]);
            o.y = pack2bf(acc[mt][nt][2], acc[mt][nt][3]);
            *(uint2*)&smem[(row * 128 + colT) ^ sx] = o;
        }
    }
    __syncthreads();
    #pragma unroll
    for (int i = 0; i < 8; i++) {
        int rr = (tid >> 4) + i * 16;
        int seg = tid & 15;
        uint4 val = *(const uint4*)&smem[(rr * 128 + seg * 8) ^ ((rr & 7) << 3)];
        int gr = row0 + rr;
        if (gr < M)
            *(uint4*)&C[(size_t)gr * N + col0 + seg * 8] = val;
    }
}

// ---------- gather1: max over in-edges + root + bias -> LN -> ReLU -> h (bf16) ----------
__global__ __launch_bounds__(256) void gather1(
    const ushort* __restrict__ xw1, const int* __restrict__ offs, const int* __restrict__ ep1,
    const float* __restrict__ bias, const float* __restrict__ g, const float* __restrict__ b,
    ushort* __restrict__ h)
{
    int n = blockIdx.x * 4 + (threadIdx.x >> 6);
    if (n >= NN) return;
    int lane = threadIdx.x & 63;
    int lane4 = lane * 4;
    int e0 = __builtin_amdgcn_readfirstlane(offs[n]);
    int e1 = __builtin_amdgcn_readfirstlane(offs[n + 1]);

    float m0 = -INFINITY, m1 = -INFINITY, m2 = -INFINITY, m3 = -INFINITY;
    int e = e0;
    for (; e + 8 <= e1; e += 8) {
        int p[8];
        #pragma unroll
        for (int j = 0; j < 8; j++) p[j] = ep1[e + j];
        ushort4 v[8];
        #pragma unroll
        for (int j = 0; j < 8; j++) v[j] = *(const ushort4*)&xw1[(size_t)(p[j] + lane4)];
        #pragma unroll
        for (int j = 0; j < 8; j++) {
            m0 = fmaxf(m0, b2f(v[j].x)); m1 = fmaxf(m1, b2f(v[j].y));
            m2 = fmaxf(m2, b2f(v[j].z)); m3 = fmaxf(m3, b2f(v[j].w));
        }
    }
    for (; e + 2 <= e1; e += 2) {
        int pa = ep1[e], pb = ep1[e + 1];
        ushort4 va = *(const ushort4*)&xw1[(size_t)(pa + lane4)];
        ushort4 vb = *(const ushort4*)&xw1[(size_t)(pb + lane4)];
        m0 = fmaxf(m0, fmaxf(b2f(va.x), b2f(vb.x)));
        m1 = fmaxf(m1, fmaxf(b2f(va.y), b2f(vb.y)));
        m2 = fmaxf(m2, fmaxf(b2f(va.z), b2f(vb.z)));
        m3 = fmaxf(m3, fmaxf(b2f(va.w), b2f(vb.w)));
    }
    for (; e < e1; e++) {
        int p = ep1[e];
        ushort4 v = *(const ushort4*)&xw1[(size_t)(p + lane4)];
        m0 = fmaxf(m0, b2f(v.x)); m1 = fmaxf(m1, b2f(v.y));
        m2 = fmaxf(m2, b2f(v.z)); m3 = fmaxf(m3, b2f(v.w));
    }
    if (e1 == e0) { m0 = m1 = m2 = m3 = 0.f; }

    ushort4 rt = *(const ushort4*)&xw1[(size_t)n * N1 + NREL * D_HID + lane4];
    int c = lane4;
    float t0 = m0 + b2f(rt.x) + bias[c + 0];
    float t1 = m1 + b2f(rt.y) + bias[c + 1];
    float t2 = m2 + b2f(rt.z) + bias[c + 2];
    float t3 = m3 + b2f(rt.w) + bias[c + 3];

    float s = t0 + t1 + t2 + t3;
    float s2 = t0 * t0 + t1 * t1 + t2 * t2 + t3 * t3;
    #pragma unroll
    for (int m = 32; m >= 1; m >>= 1) {
        s  += __shfl_xor(s,  m, 64);
        s2 += __shfl_xor(s2, m, 64);
    }
    float mu = s * (1.f / D_HID);
    float var = s2 * (1.f / D_HID) - mu * mu;
    float rs = rsqrtf(var + LN_EPS);

    ushort4 o;
    o.x = f2b(fmaxf((t0 - mu) * rs * g[c + 0] + b[c + 0], 0.f));
    o.y = f2b(fmaxf((t1 - mu) * rs * g[c + 1] + b[c + 1], 0.f));
    o.z = f2b(fmaxf((t2 - mu) * rs * g[c + 2] + b[c + 2], 0.f));
    o.w = f2b(fmaxf((t3 - mu) * rs * g[c + 3] + b[c + 3], 0.f));
    *(ushort4*)&h[(size_t)n * D_HID + c] = o;
}

// ---------- gather2: sum over in-edges + root + bias -> LN -> log_softmax -> out ----------
__global__ __launch_bounds__(256) void gather2(
    const ushort* __restrict__ xw2, const int* __restrict__ offs, const int* __restrict__ ep1,
    const float* __restrict__ bias, const float* __restrict__ g, const float* __restrict__ b,
    float* __restrict__ out)
{
    int n = blockIdx.x * 4 + (threadIdx.x >> 6);
    if (n >= NN) return;
    int lane = threadIdx.x & 63;
    int e0 = __builtin_amdgcn_readfirstlane(offs[n]);
    int e1 = __builtin_amdgcn_readfirstlane(offs[n + 1]);

    float s = 0.f;
    int e = e0;
    for (; e + 8 <= e1; e += 8) {
        int p[8];
        #pragma unroll
        for (int j = 0; j < 8; j++) p[j] = ep1[e + j] >> 2;
        float a[8];
        #pragma unroll
        for (int j = 0; j < 8; j++) a[j] = b2f(xw2[(size_t)(p[j] + lane)]);
        s += ((a[0] + a[1]) + (a[2] + a[3])) + ((a[4] + a[5]) + (a[6] + a[7]));
    }
    for (; e < e1; e++) {
        s += b2f(xw2[(size_t)((ep1[e] >> 2) + lane)]);
    }
    float v = s + b2f(xw2[(size_t)n * N2 + NREL * D_OUT + lane]) + bias[lane];

    float sm = v, s2 = v * v;
    #pragma unroll
    for (int m = 32; m >= 1; m >>= 1) {
        sm += __shfl_xor(sm, m, 64);
        s2 += __shfl_xor(s2, m, 64);
    }
    float mu = sm * (1.f / D_OUT);
    float var = s2 * (1.f / D_OUT) - mu * mu;
    float y = (v - mu) * rsqrtf(var + LN_EPS) * g[lane] + b[lane];

    float mx = y;
    #pragma unroll
    for (int m = 32; m >= 1; m >>= 1) mx = fmaxf(mx, __shfl_xor(mx, m, 64));
    float ex = __expf(y - mx);
    float se = ex;
    #pragma unroll
    for (int m = 32; m >= 1; m >>= 1) se += __shfl_xor(se, m, 64);
    out[(size_t)n * D_OUT + lane] = y - mx - logf(se);
}

extern "C" void kernel_launch(void* const* d_in, const int* in_sizes, int n_in,
                              void* d_out, int out_size, void* d_ws, size_t ws_size,
                              hipStream_t stream)
{
    const float* x      = (const float*)d_in[0];
    const int*   eidx   = (const int*)  d_in[1];
    const int*   etype  = (const int*)  d_in[2];
    const float* bases1 = (const float*)d_in[3];
    const float* comp1  = (const float*)d_in[4];
    const float* root1  = (const float*)d_in[5];
    const float* bias1  = (const float*)d_in[6];
    const float* g1     = (const float*)d_in[7];
    const float* b1     = (const float*)d_in[8];
    const float* bases2 = (const float*)d_in[9];
    const float* comp2  = (const float*)d_in[10];
    const float* root2  = (const float*)d_in[11];
    const float* bias2  = (const float*)d_in[12];
    const float* g2     = (const float*)d_in[13];
    const float* b2     = (const float*)d_in[14];

    const int* src = eidx;
    const int* dst = eidx + NE;

    char* p = (char*)d_ws;
    auto alloc = [&](size_t bytes) -> char* {
        char* r = p;
        p += (bytes + 255) & ~(size_t)255;
        return r;
    };
    ushort* xbf    = (ushort*)alloc((size_t)NN * D_IN * 2);
    ushort* w1t    = (ushort*)alloc((size_t)N1 * D_IN * 2);
    ushort* w2t    = (ushort*)alloc((size_t)N2 * D_HID * 2);
    ushort* xw1    = (ushort*)alloc((size_t)NN * N1 * 2);
    ushort* xw2    = (ushort*)alloc((size_t)NN * N2 * 2);
    ushort* h      = (ushort*)alloc((size_t)NN * D_HID * 2);
    int*    deg    = (int*)   alloc((size_t)NN * 4);
    int*    local  = (int*)   alloc((size_t)NN * 4);
    int*    bsum   = (int*)   alloc((size_t)NBLK * 4);
    int*    offs   = (int*)   alloc((size_t)(NN + 1) * 4);
    int*    cursor = (int*)   alloc((size_t)NN * 4);
    int*    ep1    = (int*)   alloc((size_t)NE * 4);

    hipMemsetAsync(deg, 0, (size_t)NN * 4, stream);
    const int SZP = D_IN * D_HID + D_HID * D_OUT + NN * D_IN + NE;
    prep_all<<<(SZP + 255) / 256, 256, 0, stream>>>(
        bases1, comp1, root1, bases2, comp2, root2, x, dst, w1t, w2t, xbf, deg);

    scan_blk<<<NBLK, 256, 0, stream>>>(deg, local, bsum);
    scan_fin<<<NBLK, 256, 0, stream>>>(local, bsum, offs, cursor);
    scatter_ep<<<(NE + 255) / 256, 256, 0, stream>>>(src, dst, etype, cursor, ep1);

    gemm_bf16<<<dim3(N1 / 128, (NN + 127) / 128), 256, 0, stream>>>(xbf, w1t, xw1, NN, N1, D_IN);
    gather1<<<(NN + 3) / 4, 256, 0, stream>>>(xw1, offs, ep1, bias1, g1, b1, h);

    gemm_bf16<<<dim3(N2 / 128, (NN + 127) / 128), 256, 0, stream>>>(h, w2t, xw2, NN, N2, D_HID);
    gather2<<<(NN + 3) / 4, 256, 0, stream>>>(xw2, offs, ep1, bias2, g2, b2, (float*)d_out);
}